// Round 1
// baseline (352.199 us; speedup 1.0000x reference)
//
#include <hip/hip_runtime.h>

typedef unsigned short u16;
typedef unsigned int   u32;
typedef __bf16 bf16x8 __attribute__((ext_vector_type(8)));
typedef float  f32x4  __attribute__((ext_vector_type(4)));

#define B_     2
#define N_     2048
#define DIM_   1024
#define HEADS_ 16
#define DH_    64
#define BH_    (B_*HEADS_)   // 32
#define ROWS_  (B_*N_)       // 4096

__device__ __forceinline__ u16 f2b(float f) {
  union { float f; u32 u; } v; v.f = f;
  u32 r = v.u + 0x7fffu + ((v.u >> 16) & 1u);
  return (u16)(r >> 16);
}
__device__ __forceinline__ float b2f(u16 h) {
  union { u32 u; float f; } v; v.u = ((u32)h) << 16;
  return v.f;
}
__device__ __forceinline__ void gload16(const void* g, void* l) {
  __builtin_amdgcn_global_load_lds(
      (const __attribute__((address_space(1))) void*)g,
      (__attribute__((address_space(3))) void*)l, 16, 0, 0);
}
__device__ __forceinline__ f32x4 mfma16(bf16x8 a, bf16x8 b, f32x4 c) {
  return __builtin_amdgcn_mfma_f32_16x16x32_bf16(a, b, c, 0, 0, 0);
}

// ---------------- RoPE tables: cos/sin (n, 32) ----------------
__global__ __launch_bounds__(256) void rope_tables(float* __restrict__ cosT,
                                                   float* __restrict__ sinT) {
  int tid = blockIdx.x * 256 + threadIdx.x;   // 65536 = 2048*32
  int n = tid >> 5, p = tid & 31;
  float freq = expf(-(2.0f * (float)p) * (9.210340371976184f / 64.0f));
  float ang = (float)n * freq;
  cosT[tid] = cosf(ang);
  sinT[tid] = sinf(ang);
}

// ---------------- LayerNorm -> bf16 ----------------
__global__ __launch_bounds__(256) void ln_kernel(const float* __restrict__ x,
    const float* __restrict__ lw, const float* __restrict__ lb,
    u16* __restrict__ xn) {
  int r = blockIdx.x, t = threadIdx.x;
  const float4* xr = (const float4*)(x + (size_t)r * DIM_);
  float4 v = xr[t];
  float s  = v.x + v.y + v.z + v.w;
  float s2 = v.x*v.x + v.y*v.y + v.z*v.z + v.w*v.w;
  #pragma unroll
  for (int off = 32; off >= 1; off >>= 1) {
    s  += __shfl_down(s, off);
    s2 += __shfl_down(s2, off);
  }
  __shared__ float ps[4], ps2[4], bc[2];
  int w = t >> 6, lane = t & 63;
  if (lane == 0) { ps[w] = s; ps2[w] = s2; }
  __syncthreads();
  if (t == 0) {
    float S = ps[0]+ps[1]+ps[2]+ps[3], S2 = ps2[0]+ps2[1]+ps2[2]+ps2[3];
    float mu = S * (1.0f/DIM_);
    float var = S2 * (1.0f/DIM_) - mu*mu;
    bc[0] = mu; bc[1] = rsqrtf(var + 1e-5f);
  }
  __syncthreads();
  float mu = bc[0], rs = bc[1];
  float4 wv = ((const float4*)lw)[t];
  float4 bv = ((const float4*)lb)[t];
  u32 lo = (u32)f2b((v.x-mu)*rs*wv.x + bv.x) | ((u32)f2b((v.y-mu)*rs*wv.y + bv.y) << 16);
  u32 hi = (u32)f2b((v.z-mu)*rs*wv.z + bv.z) | ((u32)f2b((v.w-mu)*rs*wv.w + bv.w) << 16);
  ((uint2*)xn)[(size_t)r*256 + t] = make_uint2(lo, hi);
}

// ---------------- f32 (R x C) -> bf16 transposed (C x R) ----------------
__global__ __launch_bounds__(256) void transpose_f32_bf16(const float* __restrict__ in,
    u16* __restrict__ out, int R, int C) {
  __shared__ float tile[32][33];
  int tx = threadIdx.x & 31, ty = threadIdx.x >> 5;
  int c0 = blockIdx.x * 32, r0 = blockIdx.y * 32;
  #pragma unroll
  for (int i = 0; i < 4; i++)
    tile[ty + i*8][tx] = in[(size_t)(r0 + ty + i*8) * C + c0 + tx];
  __syncthreads();
  #pragma unroll
  for (int i = 0; i < 4; i++)
    out[(size_t)(c0 + ty + i*8) * R + r0 + tx] = f2b(tile[tx][ty + i*8]);
}

// ---------------- GEMM: A (Mx K bf16) x Bt (N x K bf16) ----------------
// MODE 0: scatter epilogue into q (bh,n,d), k (bh,n,d), v^T (bh,d,n)
// MODE 1: out[r*N+c] = acc + bias[c]  (f32)
template<int MODE>
__global__ __launch_bounds__(256) void gemm_bt(
    const u16* __restrict__ A, const u16* __restrict__ Bt, int N, int K,
    u16* __restrict__ qo, u16* __restrict__ ko, u16* __restrict__ vo,
    const float* __restrict__ bias, float* __restrict__ out) {
  __shared__ __align__(16) u16 lA[128*32];
  __shared__ __align__(16) u16 lB[128*32];
  int tid = threadIdx.x;
  int lane = tid & 63;
  int w = tid >> 6, wm = w >> 1, wn = w & 1;
  int l15 = lane & 15, g = lane >> 4;
  int bm = blockIdx.x, bn = blockIdx.y;
  const f32x4 z = {0.f, 0.f, 0.f, 0.f};
  f32x4 acc[4][4];
  #pragma unroll
  for (int i = 0; i < 4; i++)
    #pragma unroll
    for (int j = 0; j < 4; j++)
      acc[i][j] = z;
  const u16* ag = A  + (size_t)(bm*128 + (tid>>2)) * K + (tid&3)*8;
  const u16* bg = Bt + (size_t)(bn*128 + (tid>>2)) * K + (tid&3)*8;
  u16* la = lA + tid*8;
  u16* lb = lB + tid*8;
  for (int k0 = 0; k0 < K; k0 += 32) {
    gload16(ag + k0,               la);
    gload16(ag + (size_t)64*K + k0, la + 2048);
    gload16(bg + k0,               lb);
    gload16(bg + (size_t)64*K + k0, lb + 2048);
    __syncthreads();
    bf16x8 af[4], bfr[4];
    #pragma unroll
    for (int mt = 0; mt < 4; mt++)
      af[mt] = *(const bf16x8*)(lA + (wm*64 + mt*16 + l15)*32 + g*8);
    #pragma unroll
    for (int nt = 0; nt < 4; nt++)
      bfr[nt] = *(const bf16x8*)(lB + (wn*64 + nt*16 + l15)*32 + g*8);
    #pragma unroll
    for (int mt = 0; mt < 4; mt++)
      #pragma unroll
      for (int nt = 0; nt < 4; nt++)
        acc[mt][nt] = mfma16(af[mt], bfr[nt], acc[mt][nt]);
    __syncthreads();
  }
  #pragma unroll
  for (int mt = 0; mt < 4; mt++) {
    #pragma unroll
    for (int nt = 0; nt < 4; nt++) {
      #pragma unroll
      for (int reg = 0; reg < 4; reg++) {
        int rr = bm*128 + wm*64 + mt*16 + g*4 + reg;
        int cc = bn*128 + wn*64 + nt*16 + l15;
        float val = acc[mt][nt][reg];
        if (MODE == 0) {
          int which = cc >> 10, inner = cc & 1023;
          int h = inner >> 6, dd = inner & 63;
          int b = rr >> 11, np = rr & 2047;
          int bh = b*HEADS_ + h;
          if (which == 0)      qo[((size_t)(bh*2048 + np))*64 + dd] = f2b(val);
          else if (which == 1) ko[((size_t)(bh*2048 + np))*64 + dd] = f2b(val);
          else                 vo[((size_t)(bh*64 + dd))*2048 + np] = f2b(val);
        } else {
          out[(size_t)rr * N + cc] = val + bias[cc];
        }
      }
    }
  }
}

// ---------------- RoPE in-place on q,k (bh,n,64); q pre-scaled ----------------
__global__ __launch_bounds__(256) void rope_kernel(u16* q, u16* k,
    const float* __restrict__ cosT, const float* __restrict__ sinT) {
  int tid = blockIdx.x * 256 + threadIdx.x;   // 65536 = BH*N
  int n = tid & 2047;
  u32* qp = (u32*)(q + (size_t)tid * 64);
  u32* kp = (u32*)(k + (size_t)tid * 64);
  const float* cp = cosT + n*32;
  const float* sp = sinT + n*32;
  #pragma unroll
  for (int p = 0; p < 32; p++) {
    float c = cp[p], s = sp[p];
    u32 uq = qp[p];
    float qe = b2f((u16)uq), qo = b2f((u16)(uq >> 16));
    qp[p] = (u32)f2b((qe*c - qo*s) * 0.125f) | ((u32)f2b((qo*c + qe*s) * 0.125f) << 16);
    u32 uk = kp[p];
    float ke = b2f((u16)uk), ko = b2f((u16)(uk >> 16));
    kp[p] = (u32)f2b(ke*c - ko*s) | ((u32)f2b(ko*c + ke*s) << 16);
  }
}

// ---------------- Flash attention ----------------
// grid (N/64, BH). 4 waves x 16 q-rows. KBLK=64.
__global__ __launch_bounds__(256) void flash_attn(
    const u16* __restrict__ qbf, const u16* __restrict__ kbf,
    const u16* __restrict__ vt, u16* __restrict__ aout) {
  __shared__ __align__(16) char p_lds[4][2048];  // per wave: 16 rows x 64 keys bf16, XOR-swizzled
  int tid = threadIdx.x;
  int w = tid >> 6, lane = tid & 63;
  int l15 = lane & 15, g = lane >> 4;
  int qb = blockIdx.x, bh = blockIdx.y;
  const f32x4 z = {0.f, 0.f, 0.f, 0.f};
  const u16* qbase = qbf + ((size_t)bh*2048 + qb*64 + w*16) * 64;
  bf16x8 qa0 = *(const bf16x8*)(qbase + l15*64 + g*8);
  bf16x8 qa1 = *(const bf16x8*)(qbase + l15*64 + 32 + g*8);
  f32x4 o[4];
  float m[4], ls[4];
  #pragma unroll
  for (int i = 0; i < 4; i++) { o[i] = z; m[i] = -1e30f; ls[i] = 0.f; }
  char* pw = p_lds[w];
  const u16* kb = kbf + (size_t)bh * 2048 * 64;
  const u16* vb = vt  + (size_t)bh * 64 * 2048;
  for (int key0 = 0; key0 < 2048; key0 += 64) {
    f32x4 st[4];
    #pragma unroll
    for (int kt = 0; kt < 4; kt++) {
      const u16* kr = kb + (size_t)(key0 + kt*16 + l15) * 64 + g*8;
      bf16x8 k0 = *(const bf16x8*)(kr);
      bf16x8 k1 = *(const bf16x8*)(kr + 32);
      f32x4 a = mfma16(qa0, k0, z);
      st[kt] = mfma16(qa1, k1, a);
    }
    float mt[4], rsum[4], alpha[4];
    #pragma unroll
    for (int r = 0; r < 4; r++)
      mt[r] = fmaxf(fmaxf(st[0][r], st[1][r]), fmaxf(st[2][r], st[3][r]));
    #pragma unroll
    for (int off = 8; off >= 1; off >>= 1)
      #pragma unroll
      for (int r = 0; r < 4; r++)
        mt[r] = fmaxf(mt[r], __shfl_xor(mt[r], off));
    #pragma unroll
    for (int r = 0; r < 4; r++) {
      float mn = fmaxf(m[r], mt[r]);
      alpha[r] = __expf(m[r] - mn);
      m[r] = mn;
      rsum[r] = 0.f;
    }
    #pragma unroll
    for (int kt = 0; kt < 4; kt++)
      #pragma unroll
      for (int r = 0; r < 4; r++) {
        float p = __expf(st[kt][r] - m[r]);
        st[kt][r] = p;
        rsum[r] += p;
      }
    #pragma unroll
    for (int off = 8; off >= 1; off >>= 1)
      #pragma unroll
      for (int r = 0; r < 4; r++)
        rsum[r] += __shfl_xor(rsum[r], off);
    #pragma unroll
    for (int r = 0; r < 4; r++)
      ls[r] = ls[r]*alpha[r] + rsum[r];
    // write P tile to wave-private LDS (row-major 16x64 bf16, XOR-swizzled)
    #pragma unroll
    for (int kt = 0; kt < 4; kt++)
      #pragma unroll
      for (int r = 0; r < 4; r++) {
        int row = g*4 + r;
        int cb = (kt*16 + l15)*2;
        *(u16*)(pw + row*128 + (cb ^ ((row&7)<<4))) = f2b(st[kt][r]);
      }
    // rescale O
    #pragma unroll
    for (int dt = 0; dt < 4; dt++)
      #pragma unroll
      for (int r = 0; r < 4; r++)
        o[dt][r] *= alpha[r];
    // PV
    #pragma unroll
    for (int kc = 0; kc < 2; kc++) {
      int ob = kc*64 + g*16;
      bf16x8 pa = *(const bf16x8*)(pw + l15*128 + (ob ^ ((l15&7)<<4)));
      #pragma unroll
      for (int dt = 0; dt < 4; dt++) {
        const u16* vr = vb + (size_t)(dt*16 + l15)*2048 + key0 + kc*32 + g*8;
        bf16x8 vf = *(const bf16x8*)(vr);
        o[dt] = mfma16(pa, vf, o[dt]);
      }
    }
  }
  int b = bh >> 4, h = bh & 15;
  #pragma unroll
  for (int dt = 0; dt < 4; dt++)
    #pragma unroll
    for (int r = 0; r < 4; r++) {
      int n = qb*64 + w*16 + g*4 + r;
      int d = dt*16 + l15;
      float val = o[dt][r] / ls[r];
      aout[((size_t)(b*2048 + n))*1024 + h*64 + d] = f2b(val);
    }
}

extern "C" void kernel_launch(void* const* d_in, const int* in_sizes, int n_in,
                              void* d_out, int out_size, void* d_ws, size_t ws_size,
                              hipStream_t stream) {
  const float* x    = (const float*)d_in[0];
  const float* lw   = (const float*)d_in[1];
  const float* lb   = (const float*)d_in[2];
  const float* wqkv = (const float*)d_in[3];
  const float* wout = (const float*)d_in[4];
  const float* bout = (const float*)d_in[5];
  float* out = (float*)d_out;

  char* ws = (char*)d_ws;
  size_t off = 0;
  auto alloc = [&](size_t bytes) {
    char* p = ws + off;
    off += (bytes + 255) & ~(size_t)255;
    return p;
  };
  u16* xn   = (u16*)alloc((size_t)ROWS_*DIM_*2);
  u16* wqt  = (u16*)alloc((size_t)3072*1024*2);
  u16* wot  = (u16*)alloc((size_t)1024*1024*2);
  u16* qb   = (u16*)alloc((size_t)BH_*2048*64*2);
  u16* kb   = (u16*)alloc((size_t)BH_*2048*64*2);
  u16* vtb  = (u16*)alloc((size_t)BH_*2048*64*2);
  u16* aout = (u16*)alloc((size_t)ROWS_*1024*2);
  float* cosT = (float*)alloc((size_t)2048*32*4);
  float* sinT = (float*)alloc((size_t)2048*32*4);

  rope_tables<<<256, 256, 0, stream>>>(cosT, sinT);
  ln_kernel<<<ROWS_, 256, 0, stream>>>(x, lw, lb, xn);
  transpose_f32_bf16<<<dim3(96, 32), 256, 0, stream>>>(wqkv, wqt, 1024, 3072);
  transpose_f32_bf16<<<dim3(32, 32), 256, 0, stream>>>(wout, wot, 1024, 1024);
  gemm_bt<0><<<dim3(32, 24), 256, 0, stream>>>(xn, wqt, 3072, 1024,
                                               qb, kb, vtb, nullptr, nullptr);
  rope_kernel<<<256, 256, 0, stream>>>(qb, kb, cosT, sinT);
  flash_attn<<<dim3(32, 32), 256, 0, stream>>>(qb, kb, vtb, aout);
  gemm_bt<1><<<dim3(32, 8), 256, 0, stream>>>(aout, wot, 1024, 1024,
                                              nullptr, nullptr, nullptr, bout, out);
}

// Round 2
// 204.584 us; speedup vs baseline: 1.7215x; 1.7215x over previous
//
#include <hip/hip_runtime.h>

typedef unsigned short u16;
typedef unsigned int   u32;
typedef __bf16 bf16x8 __attribute__((ext_vector_type(8)));
typedef float  f32x4  __attribute__((ext_vector_type(4)));

#define B_     2
#define N_     2048
#define DIM_   1024
#define HEADS_ 16
#define DH_    64
#define BH_    (B_*HEADS_)   // 32
#define ROWS_  (B_*N_)       // 4096

__device__ __forceinline__ u16 f2b(float f) {
  union { float f; u32 u; } v; v.f = f;
  u32 r = v.u + 0x7fffu + ((v.u >> 16) & 1u);
  return (u16)(r >> 16);
}
__device__ __forceinline__ float b2f(u16 h) {
  union { u32 u; float f; } v; v.u = ((u32)h) << 16;
  return v.f;
}
__device__ __forceinline__ void gload16(const void* g, void* l) {
  __builtin_amdgcn_global_load_lds(
      (const __attribute__((address_space(1))) void*)g,
      (__attribute__((address_space(3))) void*)l, 16, 0, 0);
}
__device__ __forceinline__ f32x4 mfma16(bf16x8 a, bf16x8 b, f32x4 c) {
  return __builtin_amdgcn_mfma_f32_16x16x32_bf16(a, b, c, 0, 0, 0);
}

// ---------------- RoPE tables: cos/sin (n, 32) ----------------
__global__ __launch_bounds__(256) void rope_tables(float* __restrict__ cosT,
                                                   float* __restrict__ sinT) {
  int tid = blockIdx.x * 256 + threadIdx.x;   // 65536 = 2048*32
  int n = tid >> 5, p = tid & 31;
  float freq = expf(-(2.0f * (float)p) * (9.210340371976184f / 64.0f));
  float ang = (float)n * freq;
  cosT[tid] = cosf(ang);
  sinT[tid] = sinf(ang);
}

// ---------------- LayerNorm -> bf16 ----------------
__global__ __launch_bounds__(256) void ln_kernel(const float* __restrict__ x,
    const float* __restrict__ lw, const float* __restrict__ lb,
    u16* __restrict__ xn) {
  int r = blockIdx.x, t = threadIdx.x;
  const float4* xr = (const float4*)(x + (size_t)r * DIM_);
  float4 v = xr[t];
  float s  = v.x + v.y + v.z + v.w;
  float s2 = v.x*v.x + v.y*v.y + v.z*v.z + v.w*v.w;
  #pragma unroll
  for (int off = 32; off >= 1; off >>= 1) {
    s  += __shfl_down(s, off);
    s2 += __shfl_down(s2, off);
  }
  __shared__ float ps[4], ps2[4], bc[2];
  int w = t >> 6, lane = t & 63;
  if (lane == 0) { ps[w] = s; ps2[w] = s2; }
  __syncthreads();
  if (t == 0) {
    float S = ps[0]+ps[1]+ps[2]+ps[3], S2 = ps2[0]+ps2[1]+ps2[2]+ps2[3];
    float mu = S * (1.0f/DIM_);
    float var = S2 * (1.0f/DIM_) - mu*mu;
    bc[0] = mu; bc[1] = rsqrtf(var + 1e-5f);
  }
  __syncthreads();
  float mu = bc[0], rs = bc[1];
  float4 wv = ((const float4*)lw)[t];
  float4 bv = ((const float4*)lb)[t];
  u32 lo = (u32)f2b((v.x-mu)*rs*wv.x + bv.x) | ((u32)f2b((v.y-mu)*rs*wv.y + bv.y) << 16);
  u32 hi = (u32)f2b((v.z-mu)*rs*wv.z + bv.z) | ((u32)f2b((v.w-mu)*rs*wv.w + bv.w) << 16);
  ((uint2*)xn)[(size_t)r*256 + t] = make_uint2(lo, hi);
}

// ---------------- f32 (R x C) -> bf16 transposed (C x R) ----------------
__global__ __launch_bounds__(256) void transpose_f32_bf16(const float* __restrict__ in,
    u16* __restrict__ out, int R, int C) {
  __shared__ float tile[32][33];
  int tx = threadIdx.x & 31, ty = threadIdx.x >> 5;
  int c0 = blockIdx.x * 32, r0 = blockIdx.y * 32;
  #pragma unroll
  for (int i = 0; i < 4; i++)
    tile[ty + i*8][tx] = in[(size_t)(r0 + ty + i*8) * C + c0 + tx];
  __syncthreads();
  #pragma unroll
  for (int i = 0; i < 4; i++)
    out[(size_t)(c0 + ty + i*8) * R + r0 + tx] = f2b(tile[tx][ty + i*8]);
}

// ---------------- GEMM: A (M x K bf16) x Bt (N x K bf16) ----------------
// MODE 0: scatter epilogue into q (bh,n,d), k (bh,n,d), v^T (bh,d,n)
// MODE 1: out[r*N+c] = acc + bias[c]  (f32)
template<int MODE>
__global__ __launch_bounds__(256) void gemm_bt(
    const u16* __restrict__ A, const u16* __restrict__ Bt, int N, int K,
    u16* __restrict__ qo, u16* __restrict__ ko, u16* __restrict__ vo,
    const float* __restrict__ bias, float* __restrict__ out) {
  __shared__ __align__(16) u16 lA[128*32];
  __shared__ __align__(16) u16 lB[128*32];
  int tid = threadIdx.x;
  int lane = tid & 63;
  int w = tid >> 6, wm = w >> 1, wn = w & 1;
  int l15 = lane & 15, g = lane >> 4;
  int bm = blockIdx.x, bn = blockIdx.y;
  const f32x4 z = {0.f, 0.f, 0.f, 0.f};
  f32x4 acc[4][4];
  #pragma unroll
  for (int i = 0; i < 4; i++)
    #pragma unroll
    for (int j = 0; j < 4; j++)
      acc[i][j] = z;
  const u16* ag = A  + (size_t)(bm*128 + (tid>>2)) * K + (tid&3)*8;
  const u16* bg = Bt + (size_t)(bn*128 + (tid>>2)) * K + (tid&3)*8;
  u16* la = lA + tid*8;
  u16* lb = lB + tid*8;
  for (int k0 = 0; k0 < K; k0 += 32) {
    gload16(ag + k0,               la);
    gload16(ag + (size_t)64*K + k0, la + 2048);
    gload16(bg + k0,               lb);
    gload16(bg + (size_t)64*K + k0, lb + 2048);
    __syncthreads();
    bf16x8 af[4], bfr[4];
    #pragma unroll
    for (int mt = 0; mt < 4; mt++)
      af[mt] = *(const bf16x8*)(lA + (wm*64 + mt*16 + l15)*32 + g*8);
    #pragma unroll
    for (int nt = 0; nt < 4; nt++)
      bfr[nt] = *(const bf16x8*)(lB + (wn*64 + nt*16 + l15)*32 + g*8);
    #pragma unroll
    for (int mt = 0; mt < 4; mt++)
      #pragma unroll
      for (int nt = 0; nt < 4; nt++)
        acc[mt][nt] = mfma16(af[mt], bfr[nt], acc[mt][nt]);
    __syncthreads();
  }
  #pragma unroll
  for (int mt = 0; mt < 4; mt++) {
    #pragma unroll
    for (int nt = 0; nt < 4; nt++) {
      #pragma unroll
      for (int reg = 0; reg < 4; reg++) {
        int rr = bm*128 + wm*64 + mt*16 + g*4 + reg;
        int cc = bn*128 + wn*64 + nt*16 + l15;
        float val = acc[mt][nt][reg];
        if (MODE == 0) {
          int which = cc >> 10, inner = cc & 1023;
          int h = inner >> 6, dd = inner & 63;
          int b = rr >> 11, np = rr & 2047;
          int bh = b*HEADS_ + h;
          if (which == 0)      qo[((size_t)(bh*2048 + np))*64 + dd] = f2b(val);
          else if (which == 1) ko[((size_t)(bh*2048 + np))*64 + dd] = f2b(val);
          else                 vo[((size_t)(bh*64 + dd))*2048 + np] = f2b(val);
        } else {
          out[(size_t)rr * N + cc] = val + bias[cc];
        }
      }
    }
  }
}

// ---------------- RoPE in-place on q,k (bh,n,64); q pre-scaled ----------------
__global__ __launch_bounds__(256) void rope_kernel(u16* q, u16* k,
    const float* __restrict__ cosT, const float* __restrict__ sinT) {
  int tid = blockIdx.x * 256 + threadIdx.x;   // 65536 = BH*N
  int n = tid & 2047;
  u32* qp = (u32*)(q + (size_t)tid * 64);
  u32* kp = (u32*)(k + (size_t)tid * 64);
  const float* cp = cosT + n*32;
  const float* sp = sinT + n*32;
  #pragma unroll
  for (int p = 0; p < 32; p++) {
    float c = cp[p], s = sp[p];
    u32 uq = qp[p];
    float qe = b2f((u16)uq), qo = b2f((u16)(uq >> 16));
    qp[p] = (u32)f2b((qe*c - qo*s) * 0.125f) | ((u32)f2b((qo*c + qe*s) * 0.125f) << 16);
    u32 uk = kp[p];
    float ke = b2f((u16)uk), ko = b2f((u16)(uk >> 16));
    kp[p] = (u32)f2b(ke*c - ko*s) | ((u32)f2b(ko*c + ke*s) << 16);
  }
}

// ---------------- Flash attention (restructured) ----------------
// grid (N/64, BH), 4 waves x 16 q-rows. KBLK=64.
// K,V staged in LDS (double-buffered, global_load_lds, source-pre-swizzled).
// Swapped QK^T: S^T = mfma(K_frag, Q_frag) -> lane owns q-col (l15), 16 keys.
// PV: O^T = mfma(V^T_frag, P^T_frag). O transposed via LDS at the end.
__global__ __launch_bounds__(256) void flash_attn(
    const u16* __restrict__ qbf, const u16* __restrict__ kbf,
    const u16* __restrict__ vt, u16* __restrict__ aout) {
  __shared__ __align__(16) char lK[2][8192];   // [key 64][128B], swizzled
  __shared__ __align__(16) char lV[2][8192];   // [d 64][128B], swizzled
  __shared__ __align__(16) char pl[4][2048];   // per-wave P / O-transpose buf
  int tid = threadIdx.x;
  int w = tid >> 6, lane = tid & 63;
  int l15 = lane & 15, g = lane >> 4;
  int qb = blockIdx.x, bh = blockIdx.y;
  const f32x4 z = {0.f, 0.f, 0.f, 0.f};
  const u16* qbase = qbf + ((size_t)bh*2048 + qb*64 + w*16) * 64;
  bf16x8 qa0 = *(const bf16x8*)(qbase + l15*64 + g*8);
  bf16x8 qa1 = *(const bf16x8*)(qbase + l15*64 + 32 + g*8);
  const char* kb = (const char*)(kbf + (size_t)bh * 2048 * 64);
  const char* vb = (const char*)(vt  + (size_t)bh * 64 * 2048);
  // per-lane pre-swizzled source slot within a 128B row
  int soff = ((lane & 7) * 16) ^ ((lane >> 3) << 4);
  int rl = lane >> 3;            // row-within-8 for staging
  char* pw = pl[w];
  const int swz  = (l15 & 7) << 4;   // K/V read swizzle (by row&7)
  const int swz2 = (l15 & 3) << 5;   // P swizzle (16B-preserving)

  float m = -1e30f, ls = 0.f;
  f32x4 o[4];
  #pragma unroll
  for (int i = 0; i < 4; i++) o[i] = z;

  // prologue stage (key0 = 0) into buf 0
  #pragma unroll
  for (int j = 0; j < 2; j++) {
    int row = w*16 + j*8 + rl;
    gload16(kb + (size_t)row * 128 + soff,  &lK[0][w*2048 + j*1024]);
    gload16(vb + (size_t)row * 4096 + soff, &lV[0][w*2048 + j*1024]);
  }
  __syncthreads();
  int cur = 0;

  for (int t = 0; t < 32; t++) {
    if (t < 31) {
      int key0 = (t + 1) * 64;
      #pragma unroll
      for (int j = 0; j < 2; j++) {
        int row = w*16 + j*8 + rl;
        gload16(kb + (size_t)(key0 + row) * 128 + soff,
                &lK[cur ^ 1][w*2048 + j*1024]);
        gload16(vb + (size_t)row * 4096 + (size_t)key0 * 2 + soff,
                &lV[cur ^ 1][w*2048 + j*1024]);
      }
    }
    const char* Kc = lK[cur];
    const char* Vc = lV[cur];
    // QK^T (swapped): st[kt] holds S^T[key = kt*16+g*4+r][q = l15]
    f32x4 st[4];
    #pragma unroll
    for (int kt = 0; kt < 4; kt++) {
      const char* krow = Kc + (kt*16 + l15) * 128;
      bf16x8 k0 = *(const bf16x8*)(krow + ((g*16) ^ swz));
      bf16x8 k1 = *(const bf16x8*)(krow + ((64 + g*16) ^ swz));
      f32x4 a = mfma16(k0, qa0, z);
      st[kt] = mfma16(k1, qa1, a);
    }
    // online softmax: lane owns 16 keys of q-col l15
    float mt = fmaxf(fmaxf(st[0][0], st[0][1]), fmaxf(st[0][2], st[0][3]));
    #pragma unroll
    for (int kt = 1; kt < 4; kt++)
      mt = fmaxf(mt, fmaxf(fmaxf(st[kt][0], st[kt][1]),
                           fmaxf(st[kt][2], st[kt][3])));
    mt = fmaxf(mt, __shfl_xor(mt, 16));
    mt = fmaxf(mt, __shfl_xor(mt, 32));
    float mn = fmaxf(m, mt);
    float alpha = __expf(m - mn);
    m = mn;
    float rs = 0.f;
    #pragma unroll
    for (int kt = 0; kt < 4; kt++)
      #pragma unroll
      for (int r = 0; r < 4; r++) {
        float p = __expf(st[kt][r] - mn);
        st[kt][r] = p;
        rs += p;
      }
    rs += __shfl_xor(rs, 16);
    rs += __shfl_xor(rs, 32);
    ls = ls * alpha + rs;
    // pack P -> wave-private LDS row q=l15, bytes = key*2 (swizzled)
    #pragma unroll
    for (int kt = 0; kt < 4; kt++) {
      u32 lo = (u32)f2b(st[kt][0]) | ((u32)f2b(st[kt][1]) << 16);
      u32 hi = (u32)f2b(st[kt][2]) | ((u32)f2b(st[kt][3]) << 16);
      *(uint2*)(pw + l15*128 + ((kt*32 + g*8) ^ swz2)) = make_uint2(lo, hi);
    }
    // rescale O
    #pragma unroll
    for (int dt = 0; dt < 4; dt++)
      #pragma unroll
      for (int r = 0; r < 4; r++)
        o[dt][r] *= alpha;
    // P^T B-frags: lane = (q=l15, keys g*8..+7) per 32-key chunk
    bf16x8 pb0 = *(const bf16x8*)(pw + l15*128 + ((g*16) ^ swz2));
    bf16x8 pb1 = *(const bf16x8*)(pw + l15*128 + ((64 + g*16) ^ swz2));
    // PV: O^T[d = dt*16+g*4+r][q = l15]
    #pragma unroll
    for (int dt = 0; dt < 4; dt++) {
      const char* vrow = Vc + (dt*16 + l15) * 128;
      bf16x8 v0 = *(const bf16x8*)(vrow + ((g*16) ^ swz));
      bf16x8 v1 = *(const bf16x8*)(vrow + ((64 + g*16) ^ swz));
      o[dt] = mfma16(v0, pb0, o[dt]);
      o[dt] = mfma16(v1, pb1, o[dt]);
    }
    __syncthreads();
    cur ^= 1;
  }

  // epilogue: O^T -> O via wave-private LDS, coalesced 16B stores
  float rls = 1.0f / ls;
  #pragma unroll
  for (int dt = 0; dt < 4; dt++)
    #pragma unroll
    for (int r = 0; r < 4; r++) {
      int d = dt*16 + g*4 + r;
      *(u16*)(pw + l15*128 + ((d*2) ^ swz)) = f2b(o[dt][r] * rls);
    }
  int b = bh >> 4, h = bh & 15;
  #pragma unroll
  for (int i = 0; i < 2; i++) {
    int row = i*8 + rl;          // local q row
    uint4 ov = *(const uint4*)(pw + row*128 + (((lane & 7)*16) ^ (rl << 4)));
    int n = qb*64 + w*16 + row;
    *(uint4*)(aout + ((size_t)(b*2048 + n))*1024 + h*64 + (lane & 7)*8) = ov;
  }
}

extern "C" void kernel_launch(void* const* d_in, const int* in_sizes, int n_in,
                              void* d_out, int out_size, void* d_ws, size_t ws_size,
                              hipStream_t stream) {
  const float* x    = (const float*)d_in[0];
  const float* lw   = (const float*)d_in[1];
  const float* lb   = (const float*)d_in[2];
  const float* wqkv = (const float*)d_in[3];
  const float* wout = (const float*)d_in[4];
  const float* bout = (const float*)d_in[5];
  float* out = (float*)d_out;

  char* ws = (char*)d_ws;
  size_t off = 0;
  auto alloc = [&](size_t bytes) {
    char* p = ws + off;
    off += (bytes + 255) & ~(size_t)255;
    return p;
  };
  u16* xn   = (u16*)alloc((size_t)ROWS_*DIM_*2);
  u16* wqt  = (u16*)alloc((size_t)3072*1024*2);
  u16* wot  = (u16*)alloc((size_t)1024*1024*2);
  u16* qb   = (u16*)alloc((size_t)BH_*2048*64*2);
  u16* kb   = (u16*)alloc((size_t)BH_*2048*64*2);
  u16* vtb  = (u16*)alloc((size_t)BH_*2048*64*2);
  u16* aout = (u16*)alloc((size_t)ROWS_*1024*2);
  float* cosT = (float*)alloc((size_t)2048*32*4);
  float* sinT = (float*)alloc((size_t)2048*32*4);

  rope_tables<<<256, 256, 0, stream>>>(cosT, sinT);
  ln_kernel<<<ROWS_, 256, 0, stream>>>(x, lw, lb, xn);
  transpose_f32_bf16<<<dim3(96, 32), 256, 0, stream>>>(wqkv, wqt, 1024, 3072);
  transpose_f32_bf16<<<dim3(32, 32), 256, 0, stream>>>(wout, wot, 1024, 1024);
  gemm_bt<0><<<dim3(32, 24), 256, 0, stream>>>(xn, wqt, 3072, 1024,
                                               qb, kb, vtb, nullptr, nullptr);
  rope_kernel<<<256, 256, 0, stream>>>(qb, kb, cosT, sinT);
  flash_attn<<<dim3(32, 32), 256, 0, stream>>>(qb, kb, vtb, aout);
  gemm_bt<1><<<dim3(32, 8), 256, 0, stream>>>(aout, wot, 1024, 1024,
                                              nullptr, nullptr, nullptr, bout, out);
}

// Round 3
// 157.152 us; speedup vs baseline: 2.2411x; 1.3018x over previous
//
#include <hip/hip_runtime.h>

typedef unsigned short u16;
typedef unsigned int   u32;
typedef __bf16 bf16x8 __attribute__((ext_vector_type(8)));
typedef __bf16 bf16x2 __attribute__((ext_vector_type(2)));
typedef float  f32x4  __attribute__((ext_vector_type(4)));

#define B_     2
#define N_     2048
#define DIM_   1024
#define HEADS_ 16
#define DH_    64
#define BH_    (B_*HEADS_)   // 32
#define ROWS_  (B_*N_)       // 4096

__device__ __forceinline__ u16 f2b(float f) {
  union { __bf16 h; u16 u; } v; v.h = (__bf16)f; return v.u;
}
__device__ __forceinline__ u32 pkb(float a, float b) {
  bf16x2 t; t[0] = (__bf16)a; t[1] = (__bf16)b;
  union { bf16x2 v; u32 u; } c; c.v = t; return c.u;
}
__device__ __forceinline__ float b2f(u16 h) {
  union { u32 u; float f; } v; v.u = ((u32)h) << 16;
  return v.f;
}
__device__ __forceinline__ void gload16(const void* g, void* l) {
  __builtin_amdgcn_global_load_lds(
      (const __attribute__((address_space(1))) void*)g,
      (__attribute__((address_space(3))) void*)l, 16, 0, 0);
}
__device__ __forceinline__ f32x4 mfma16(bf16x8 a, bf16x8 b, f32x4 c) {
  return __builtin_amdgcn_mfma_f32_16x16x32_bf16(a, b, c, 0, 0, 0);
}

// ---------------- RoPE tables: cos/sin (n, 32) ----------------
__global__ __launch_bounds__(256) void rope_tables(float* __restrict__ cosT,
                                                   float* __restrict__ sinT) {
  int tid = blockIdx.x * 256 + threadIdx.x;   // 65536 = 2048*32
  int n = tid >> 5, p = tid & 31;
  float freq = expf(-(2.0f * (float)p) * (9.210340371976184f / 64.0f));
  float ang = (float)n * freq;
  cosT[tid] = cosf(ang);
  sinT[tid] = sinf(ang);
}

// ---------------- LayerNorm -> bf16 ----------------
__global__ __launch_bounds__(256) void ln_kernel(const float* __restrict__ x,
    const float* __restrict__ lw, const float* __restrict__ lb,
    u16* __restrict__ xn) {
  int r = blockIdx.x, t = threadIdx.x;
  const float4* xr = (const float4*)(x + (size_t)r * DIM_);
  float4 v = xr[t];
  float s  = v.x + v.y + v.z + v.w;
  float s2 = v.x*v.x + v.y*v.y + v.z*v.z + v.w*v.w;
  #pragma unroll
  for (int off = 32; off >= 1; off >>= 1) {
    s  += __shfl_down(s, off);
    s2 += __shfl_down(s2, off);
  }
  __shared__ float ps[4], ps2[4], bc[2];
  int w = t >> 6, lane = t & 63;
  if (lane == 0) { ps[w] = s; ps2[w] = s2; }
  __syncthreads();
  if (t == 0) {
    float S = ps[0]+ps[1]+ps[2]+ps[3], S2 = ps2[0]+ps2[1]+ps2[2]+ps2[3];
    float mu = S * (1.0f/DIM_);
    float var = S2 * (1.0f/DIM_) - mu*mu;
    bc[0] = mu; bc[1] = rsqrtf(var + 1e-5f);
  }
  __syncthreads();
  float mu = bc[0], rs = bc[1];
  float4 wv = ((const float4*)lw)[t];
  float4 bv = ((const float4*)lb)[t];
  u32 lo = pkb((v.x-mu)*rs*wv.x + bv.x, (v.y-mu)*rs*wv.y + bv.y);
  u32 hi = pkb((v.z-mu)*rs*wv.z + bv.z, (v.w-mu)*rs*wv.w + bv.w);
  ((uint2*)xn)[(size_t)r*256 + t] = make_uint2(lo, hi);
}

// ---------------- f32 (R x C) -> bf16 transposed (C x R) ----------------
__global__ __launch_bounds__(256) void transpose_f32_bf16(const float* __restrict__ in,
    u16* __restrict__ out, int R, int C) {
  __shared__ float tile[32][33];
  int tx = threadIdx.x & 31, ty = threadIdx.x >> 5;
  int c0 = blockIdx.x * 32, r0 = blockIdx.y * 32;
  #pragma unroll
  for (int i = 0; i < 4; i++)
    tile[ty + i*8][tx] = in[(size_t)(r0 + ty + i*8) * C + c0 + tx];
  __syncthreads();
  #pragma unroll
  for (int i = 0; i < 4; i++)
    out[(size_t)(c0 + ty + i*8) * R + r0 + tx] = f2b(tile[tx][ty + i*8]);
}

// ---------------- GEMM: A (M x K bf16) x Bt (N x K bf16) ----------------
// MODE 0: scatter epilogue into q (bh,n,d), k (bh,n,d), v^T (bh,d,n)
// MODE 1: out[r*N+c] = acc + bias[c]  (f32)
template<int MODE>
__global__ __launch_bounds__(256) void gemm_bt(
    const u16* __restrict__ A, const u16* __restrict__ Bt, int N, int K,
    u16* __restrict__ qo, u16* __restrict__ ko, u16* __restrict__ vo,
    const float* __restrict__ bias, float* __restrict__ out) {
  __shared__ __align__(16) u16 lA[128*32];
  __shared__ __align__(16) u16 lB[128*32];
  int tid = threadIdx.x;
  int lane = tid & 63;
  int w = tid >> 6, wm = w >> 1, wn = w & 1;
  int l15 = lane & 15, g = lane >> 4;
  int bm = blockIdx.x, bn = blockIdx.y;
  const f32x4 z = {0.f, 0.f, 0.f, 0.f};
  f32x4 acc[4][4];
  #pragma unroll
  for (int i = 0; i < 4; i++)
    #pragma unroll
    for (int j = 0; j < 4; j++)
      acc[i][j] = z;
  const u16* ag = A  + (size_t)(bm*128 + (tid>>2)) * K + (tid&3)*8;
  const u16* bg = Bt + (size_t)(bn*128 + (tid>>2)) * K + (tid&3)*8;
  u16* la = lA + tid*8;
  u16* lb = lB + tid*8;
  for (int k0 = 0; k0 < K; k0 += 32) {
    gload16(ag + k0,               la);
    gload16(ag + (size_t)64*K + k0, la + 2048);
    gload16(bg + k0,               lb);
    gload16(bg + (size_t)64*K + k0, lb + 2048);
    __syncthreads();
    bf16x8 af[4], bfr[4];
    #pragma unroll
    for (int mt = 0; mt < 4; mt++)
      af[mt] = *(const bf16x8*)(lA + (wm*64 + mt*16 + l15)*32 + g*8);
    #pragma unroll
    for (int nt = 0; nt < 4; nt++)
      bfr[nt] = *(const bf16x8*)(lB + (wn*64 + nt*16 + l15)*32 + g*8);
    __builtin_amdgcn_s_setprio(1);
    #pragma unroll
    for (int mt = 0; mt < 4; mt++)
      #pragma unroll
      for (int nt = 0; nt < 4; nt++)
        acc[mt][nt] = mfma16(af[mt], bfr[nt], acc[mt][nt]);
    __builtin_amdgcn_s_setprio(0);
    __syncthreads();
  }
  #pragma unroll
  for (int mt = 0; mt < 4; mt++) {
    #pragma unroll
    for (int nt = 0; nt < 4; nt++) {
      #pragma unroll
      for (int reg = 0; reg < 4; reg++) {
        int rr = bm*128 + wm*64 + mt*16 + g*4 + reg;
        int cc = bn*128 + wn*64 + nt*16 + l15;
        float val = acc[mt][nt][reg];
        if (MODE == 0) {
          int which = cc >> 10, inner = cc & 1023;
          int h = inner >> 6, dd = inner & 63;
          int b = rr >> 11, np = rr & 2047;
          int bh = b*HEADS_ + h;
          if (which == 0)      qo[((size_t)(bh*2048 + np))*64 + dd] = f2b(val);
          else if (which == 1) ko[((size_t)(bh*2048 + np))*64 + dd] = f2b(val);
          else                 vo[((size_t)(bh*64 + dd))*2048 + np] = f2b(val);
        } else {
          out[(size_t)rr * N + cc] = val + bias[cc];
        }
      }
    }
  }
}

// ---------------- RoPE in-place on q,k (bh,n,64); coalesced ----------------
// q additionally scaled by DH^-1/2 * log2(e)  (scores land in log2 domain)
__global__ __launch_bounds__(256) void rope_kernel(u16* q, u16* k,
    const float* __restrict__ cosT, const float* __restrict__ sinT) {
  int tid = blockIdx.x * 256 + threadIdx.x;   // 524288 = BH*N*8
  int row = tid >> 3, sub = tid & 7;
  int n = row & 2047;
  u32* qp = (u32*)(q + (size_t)row * 64 + sub * 8);
  u32* kp = (u32*)(k + (size_t)row * 64 + sub * 8);
  uint4 uq = *(uint4*)qp;
  uint4 uk = *(uint4*)kp;
  float4 c4 = *(const float4*)(cosT + n*32 + sub*4);
  float4 s4 = *(const float4*)(sinT + n*32 + sub*4);
  const float qs = 0.125f * 1.4426950408889634f;
#define ROPE_Q(u, c, s) { \
    float e = b2f((u16)(u)), o = b2f((u16)((u) >> 16)); \
    (u) = pkb((e*(c) - o*(s))*qs, (o*(c) + e*(s))*qs); }
#define ROPE_K(u, c, s) { \
    float e = b2f((u16)(u)), o = b2f((u16)((u) >> 16)); \
    (u) = pkb(e*(c) - o*(s), o*(c) + e*(s)); }
  ROPE_Q(uq.x, c4.x, s4.x) ROPE_Q(uq.y, c4.y, s4.y)
  ROPE_Q(uq.z, c4.z, s4.z) ROPE_Q(uq.w, c4.w, s4.w)
  ROPE_K(uk.x, c4.x, s4.x) ROPE_K(uk.y, c4.y, s4.y)
  ROPE_K(uk.z, c4.z, s4.z) ROPE_K(uk.w, c4.w, s4.w)
#undef ROPE_Q
#undef ROPE_K
  *(uint4*)qp = uq;
  *(uint4*)kp = uk;
}

// ---------------- Flash attention ----------------
// grid (N/64, BH), 4 waves x 16 q-rows. KBLK=64. Scores in log2 domain.
// K,V staged in LDS (double-buffered, global_load_lds, source-pre-swizzled).
// Swapped QK^T: S^T = mfma(K_frag, Q_frag) -> lane owns q-col (l15), 16 keys.
// PV: O^T = mfma(V^T_frag, P^T_frag). O transposed via LDS at the end.
__global__ __launch_bounds__(256) void flash_attn(
    const u16* __restrict__ qbf, const u16* __restrict__ kbf,
    const u16* __restrict__ vt, u16* __restrict__ aout) {
  __shared__ __align__(16) char lK[2][8192];   // [key 64][128B], swizzled
  __shared__ __align__(16) char lV[2][8192];   // [d 64][128B], swizzled
  __shared__ __align__(16) char pl[4][2048];   // per-wave P / O-transpose buf
  int tid = threadIdx.x;
  int w = tid >> 6, lane = tid & 63;
  int l15 = lane & 15, g = lane >> 4;
  int qb = blockIdx.x, bh = blockIdx.y;
  const f32x4 z = {0.f, 0.f, 0.f, 0.f};
  const u16* qbase = qbf + ((size_t)bh*2048 + qb*64 + w*16) * 64;
  bf16x8 qa0 = *(const bf16x8*)(qbase + l15*64 + g*8);
  bf16x8 qa1 = *(const bf16x8*)(qbase + l15*64 + 32 + g*8);
  const char* kb = (const char*)(kbf + (size_t)bh * 2048 * 64);
  const char* vb = (const char*)(vt  + (size_t)bh * 64 * 2048);
  // per-lane pre-swizzled source slot within a 128B row
  int soff = ((lane & 7) * 16) ^ ((lane >> 3) << 4);
  int rl = lane >> 3;            // row-within-8 for staging
  char* pw = pl[w];
  const int swz = (l15 & 7) << 4;   // row-XOR swizzle (K/V/P, same involution)

  float m = -1e30f, ls = 0.f;
  f32x4 o[4];
  #pragma unroll
  for (int i = 0; i < 4; i++) o[i] = z;

  // prologue stage (key0 = 0) into buf 0
  #pragma unroll
  for (int j = 0; j < 2; j++) {
    int row = w*16 + j*8 + rl;
    gload16(kb + (size_t)row * 128 + soff,  &lK[0][w*2048 + j*1024]);
    gload16(vb + (size_t)row * 4096 + soff, &lV[0][w*2048 + j*1024]);
  }
  __syncthreads();
  int cur = 0;

  for (int t = 0; t < 32; t++) {
    if (t < 31) {
      int key0 = (t + 1) * 64;
      #pragma unroll
      for (int j = 0; j < 2; j++) {
        int row = w*16 + j*8 + rl;
        gload16(kb + (size_t)(key0 + row) * 128 + soff,
                &lK[cur ^ 1][w*2048 + j*1024]);
        gload16(vb + (size_t)row * 4096 + (size_t)key0 * 2 + soff,
                &lV[cur ^ 1][w*2048 + j*1024]);
      }
    }
    const char* Kc = lK[cur];
    const char* Vc = lV[cur];
    // QK^T (swapped): st[kt] holds S^T[key = kt*16+g*4+r][q = l15]
    f32x4 st[4];
    __builtin_amdgcn_s_setprio(1);
    #pragma unroll
    for (int kt = 0; kt < 4; kt++) {
      const char* krow = Kc + (kt*16 + l15) * 128;
      bf16x8 k0 = *(const bf16x8*)(krow + ((g*16) ^ swz));
      bf16x8 k1 = *(const bf16x8*)(krow + ((64 + g*16) ^ swz));
      f32x4 a = mfma16(k0, qa0, z);
      st[kt] = mfma16(k1, qa1, a);
    }
    __builtin_amdgcn_s_setprio(0);
    // online softmax (log2 domain): lane owns 16 keys of q-col l15
    float mt = fmaxf(fmaxf(st[0][0], st[0][1]), fmaxf(st[0][2], st[0][3]));
    #pragma unroll
    for (int kt = 1; kt < 4; kt++)
      mt = fmaxf(mt, fmaxf(fmaxf(st[kt][0], st[kt][1]),
                           fmaxf(st[kt][2], st[kt][3])));
    mt = fmaxf(mt, __shfl_xor(mt, 16));
    mt = fmaxf(mt, __shfl_xor(mt, 32));
    // defer-max: only rescale when tile max grew past threshold
    if (__any(mt > m + 8.0f)) {
      float mn = fmaxf(m, mt);
      float al = __builtin_amdgcn_exp2f(m - mn);
      m = mn;
      ls *= al;
      #pragma unroll
      for (int dt = 0; dt < 4; dt++)
        #pragma unroll
        for (int r = 0; r < 4; r++)
          o[dt][r] *= al;
    }
    float rs = 0.f;
    #pragma unroll
    for (int kt = 0; kt < 4; kt++)
      #pragma unroll
      for (int r = 0; r < 4; r++) {
        float p = __builtin_amdgcn_exp2f(st[kt][r] - m);
        st[kt][r] = p;
        rs += p;
      }
    rs += __shfl_xor(rs, 16);
    rs += __shfl_xor(rs, 32);
    ls += rs;
    // pack P -> wave-private LDS row q=l15, bytes = key*2 (swizzled)
    #pragma unroll
    for (int kt = 0; kt < 4; kt++) {
      u32 lo = pkb(st[kt][0], st[kt][1]);
      u32 hi = pkb(st[kt][2], st[kt][3]);
      *(uint2*)(pw + l15*128 + ((kt*32 + g*8) ^ swz)) = make_uint2(lo, hi);
    }
    // P^T B-frags: lane = (q=l15, keys g*8..+7) per 32-key chunk
    bf16x8 pb0 = *(const bf16x8*)(pw + l15*128 + ((g*16) ^ swz));
    bf16x8 pb1 = *(const bf16x8*)(pw + l15*128 + ((64 + g*16) ^ swz));
    // PV: O^T[d = dt*16+g*4+r][q = l15]
    __builtin_amdgcn_s_setprio(1);
    #pragma unroll
    for (int dt = 0; dt < 4; dt++) {
      const char* vrow = Vc + (dt*16 + l15) * 128;
      bf16x8 v0 = *(const bf16x8*)(vrow + ((g*16) ^ swz));
      bf16x8 v1 = *(const bf16x8*)(vrow + ((64 + g*16) ^ swz));
      o[dt] = mfma16(v0, pb0, o[dt]);
      o[dt] = mfma16(v1, pb1, o[dt]);
    }
    __builtin_amdgcn_s_setprio(0);
    __syncthreads();
    cur ^= 1;
  }

  // epilogue: O^T -> O via wave-private LDS, coalesced 16B stores
  float rls = 1.0f / ls;
  #pragma unroll
  for (int dt = 0; dt < 4; dt++)
    #pragma unroll
    for (int r = 0; r < 4; r++) {
      int d = dt*16 + g*4 + r;
      *(u16*)(pw + l15*128 + ((d*2) ^ swz)) = f2b(o[dt][r] * rls);
    }
  int b = bh >> 4, h = bh & 15;
  #pragma unroll
  for (int i = 0; i < 2; i++) {
    int row = i*8 + rl;          // local q row
    uint4 ov = *(const uint4*)(pw + row*128 + (((lane & 7)*16) ^ (rl << 4)));
    int n = qb*64 + w*16 + row;
    *(uint4*)(aout + ((size_t)(b*2048 + n))*1024 + h*64 + (lane & 7)*8) = ov;
  }
}

extern "C" void kernel_launch(void* const* d_in, const int* in_sizes, int n_in,
                              void* d_out, int out_size, void* d_ws, size_t ws_size,
                              hipStream_t stream) {
  const float* x    = (const float*)d_in[0];
  const float* lw   = (const float*)d_in[1];
  const float* lb   = (const float*)d_in[2];
  const float* wqkv = (const float*)d_in[3];
  const float* wout = (const float*)d_in[4];
  const float* bout = (const float*)d_in[5];
  float* out = (float*)d_out;

  char* ws = (char*)d_ws;
  size_t off = 0;
  auto alloc = [&](size_t bytes) {
    char* p = ws + off;
    off += (bytes + 255) & ~(size_t)255;
    return p;
  };
  u16* xn   = (u16*)alloc((size_t)ROWS_*DIM_*2);
  u16* wqt  = (u16*)alloc((size_t)3072*1024*2);
  u16* wot  = (u16*)alloc((size_t)1024*1024*2);
  u16* qb   = (u16*)alloc((size_t)BH_*2048*64*2);
  u16* kb   = (u16*)alloc((size_t)BH_*2048*64*2);
  u16* vtb  = (u16*)alloc((size_t)BH_*2048*64*2);
  u16* aout = (u16*)alloc((size_t)ROWS_*1024*2);
  float* cosT = (float*)alloc((size_t)2048*32*4);
  float* sinT = (float*)alloc((size_t)2048*32*4);

  rope_tables<<<256, 256, 0, stream>>>(cosT, sinT);
  ln_kernel<<<ROWS_, 256, 0, stream>>>(x, lw, lb, xn);
  transpose_f32_bf16<<<dim3(96, 32), 256, 0, stream>>>(wqkv, wqt, 1024, 3072);
  transpose_f32_bf16<<<dim3(32, 32), 256, 0, stream>>>(wout, wot, 1024, 1024);
  gemm_bt<0><<<dim3(32, 24), 256, 0, stream>>>(xn, wqt, 3072, 1024,
                                               qb, kb, vtb, nullptr, nullptr);
  rope_kernel<<<2048, 256, 0, stream>>>(qb, kb, cosT, sinT);
  flash_attn<<<dim3(32, 32), 256, 0, stream>>>(qb, kb, vtb, aout);
  gemm_bt<1><<<dim3(32, 8), 256, 0, stream>>>(aout, wot, 1024, 1024,
                                              nullptr, nullptr, nullptr, bout, out);
}

// Round 4
// 148.829 us; speedup vs baseline: 2.3665x; 1.0559x over previous
//
#include <hip/hip_runtime.h>

typedef unsigned short u16;
typedef unsigned int   u32;
typedef __bf16 bf16x8 __attribute__((ext_vector_type(8)));
typedef __bf16 bf16x2 __attribute__((ext_vector_type(2)));
typedef float  f32x4  __attribute__((ext_vector_type(4)));

#define B_     2
#define N_     2048
#define DIM_   1024
#define HEADS_ 16
#define DH_    64
#define BH_    (B_*HEADS_)   // 32
#define ROWS_  (B_*N_)       // 4096

__device__ __forceinline__ u16 f2b(float f) {
  union { __bf16 h; u16 u; } v; v.h = (__bf16)f; return v.u;
}
__device__ __forceinline__ u32 pkb(float a, float b) {
  bf16x2 t; t[0] = (__bf16)a; t[1] = (__bf16)b;
  union { bf16x2 v; u32 u; } c; c.v = t; return c.u;
}
__device__ __forceinline__ float b2f(u16 h) {
  union { u32 u; float f; } v; v.u = ((u32)h) << 16;
  return v.f;
}
__device__ __forceinline__ void gload16(const void* g, void* l) {
  __builtin_amdgcn_global_load_lds(
      (const __attribute__((address_space(1))) void*)g,
      (__attribute__((address_space(3))) void*)l, 16, 0, 0);
}
__device__ __forceinline__ f32x4 mfma16(bf16x8 a, bf16x8 b, f32x4 c) {
  return __builtin_amdgcn_mfma_f32_16x16x32_bf16(a, b, c, 0, 0, 0);
}

// ---------------- RoPE tables: cos/sin (n, 32) ----------------
__global__ __launch_bounds__(256) void rope_tables(float* __restrict__ cosT,
                                                   float* __restrict__ sinT) {
  int tid = blockIdx.x * 256 + threadIdx.x;   // 65536 = 2048*32
  int n = tid >> 5, p = tid & 31;
  float freq = expf(-(2.0f * (float)p) * (9.210340371976184f / 64.0f));
  float ang = (float)n * freq;
  cosT[tid] = cosf(ang);
  sinT[tid] = sinf(ang);
}

// ---------------- LayerNorm -> bf16 ----------------
__global__ __launch_bounds__(256) void ln_kernel(const float* __restrict__ x,
    const float* __restrict__ lw, const float* __restrict__ lb,
    u16* __restrict__ xn) {
  int r = blockIdx.x, t = threadIdx.x;
  const float4* xr = (const float4*)(x + (size_t)r * DIM_);
  float4 v = xr[t];
  float s  = v.x + v.y + v.z + v.w;
  float s2 = v.x*v.x + v.y*v.y + v.z*v.z + v.w*v.w;
  #pragma unroll
  for (int off = 32; off >= 1; off >>= 1) {
    s  += __shfl_down(s, off);
    s2 += __shfl_down(s2, off);
  }
  __shared__ float ps[4], ps2[4], bc[2];
  int w = t >> 6, lane = t & 63;
  if (lane == 0) { ps[w] = s; ps2[w] = s2; }
  __syncthreads();
  if (t == 0) {
    float S = ps[0]+ps[1]+ps[2]+ps[3], S2 = ps2[0]+ps2[1]+ps2[2]+ps2[3];
    float mu = S * (1.0f/DIM_);
    float var = S2 * (1.0f/DIM_) - mu*mu;
    bc[0] = mu; bc[1] = rsqrtf(var + 1e-5f);
  }
  __syncthreads();
  float mu = bc[0], rs = bc[1];
  float4 wv = ((const float4*)lw)[t];
  float4 bv = ((const float4*)lb)[t];
  u32 lo = pkb((v.x-mu)*rs*wv.x + bv.x, (v.y-mu)*rs*wv.y + bv.y);
  u32 hi = pkb((v.z-mu)*rs*wv.z + bv.z, (v.w-mu)*rs*wv.w + bv.w);
  ((uint2*)xn)[(size_t)r*256 + t] = make_uint2(lo, hi);
}

// ---------------- f32 (R x C) -> bf16 transposed (C x R) ----------------
__global__ __launch_bounds__(256) void transpose_f32_bf16(const float* __restrict__ in,
    u16* __restrict__ out, int R, int C) {
  __shared__ float tile[32][33];
  int tx = threadIdx.x & 31, ty = threadIdx.x >> 5;
  int c0 = blockIdx.x * 32, r0 = blockIdx.y * 32;
  #pragma unroll
  for (int i = 0; i < 4; i++)
    tile[ty + i*8][tx] = in[(size_t)(r0 + ty + i*8) * C + c0 + tx];
  __syncthreads();
  #pragma unroll
  for (int i = 0; i < 4; i++)
    out[(size_t)(c0 + ty + i*8) * R + r0 + tx] = f2b(tile[tx][ty + i*8]);
}

// ---------------- GEMM: A (M x K bf16) x Bt (N x K bf16) ----------------
// MODE 0: scatter epilogue into q (bh,n,d), k (bh,n,d), v^T (bh,d,n)
// MODE 1: out[r*N+c] = acc + bias[c]  (f32)
template<int MODE>
__global__ __launch_bounds__(256) void gemm_bt(
    const u16* __restrict__ A, const u16* __restrict__ Bt, int N, int K,
    u16* __restrict__ qo, u16* __restrict__ ko, u16* __restrict__ vo,
    const float* __restrict__ bias, float* __restrict__ out) {
  __shared__ __align__(16) u16 lA[128*32];
  __shared__ __align__(16) u16 lB[128*32];
  int tid = threadIdx.x;
  int lane = tid & 63;
  int w = tid >> 6, wm = w >> 1, wn = w & 1;
  int l15 = lane & 15, g = lane >> 4;
  int bm = blockIdx.x, bn = blockIdx.y;
  const f32x4 z = {0.f, 0.f, 0.f, 0.f};
  f32x4 acc[4][4];
  #pragma unroll
  for (int i = 0; i < 4; i++)
    #pragma unroll
    for (int j = 0; j < 4; j++)
      acc[i][j] = z;
  const u16* ag = A  + (size_t)(bm*128 + (tid>>2)) * K + (tid&3)*8;
  const u16* bg = Bt + (size_t)(bn*128 + (tid>>2)) * K + (tid&3)*8;
  u16* la = lA + tid*8;
  u16* lb = lB + tid*8;
  for (int k0 = 0; k0 < K; k0 += 32) {
    gload16(ag + k0,               la);
    gload16(ag + (size_t)64*K + k0, la + 2048);
    gload16(bg + k0,               lb);
    gload16(bg + (size_t)64*K + k0, lb + 2048);
    __syncthreads();
    bf16x8 af[4], bfr[4];
    #pragma unroll
    for (int mt = 0; mt < 4; mt++)
      af[mt] = *(const bf16x8*)(lA + (wm*64 + mt*16 + l15)*32 + g*8);
    #pragma unroll
    for (int nt = 0; nt < 4; nt++)
      bfr[nt] = *(const bf16x8*)(lB + (wn*64 + nt*16 + l15)*32 + g*8);
    __builtin_amdgcn_s_setprio(1);
    #pragma unroll
    for (int mt = 0; mt < 4; mt++)
      #pragma unroll
      for (int nt = 0; nt < 4; nt++)
        acc[mt][nt] = mfma16(af[mt], bfr[nt], acc[mt][nt]);
    __builtin_amdgcn_s_setprio(0);
    __syncthreads();
  }
  #pragma unroll
  for (int mt = 0; mt < 4; mt++) {
    #pragma unroll
    for (int nt = 0; nt < 4; nt++) {
      #pragma unroll
      for (int reg = 0; reg < 4; reg++) {
        int rr = bm*128 + wm*64 + mt*16 + g*4 + reg;
        int cc = bn*128 + wn*64 + nt*16 + l15;
        float val = acc[mt][nt][reg];
        if (MODE == 0) {
          int which = cc >> 10, inner = cc & 1023;
          int h = inner >> 6, dd = inner & 63;
          int b = rr >> 11, np = rr & 2047;
          int bh = b*HEADS_ + h;
          if (which == 0)      qo[((size_t)(bh*2048 + np))*64 + dd] = f2b(val);
          else if (which == 1) ko[((size_t)(bh*2048 + np))*64 + dd] = f2b(val);
          else                 vo[((size_t)(bh*64 + dd))*2048 + np] = f2b(val);
        } else {
          out[(size_t)rr * N + cc] = val + bias[cc];
        }
      }
    }
  }
}

// ---------------- RoPE in-place on q,k (bh,n,64); coalesced ----------------
// q additionally scaled by DH^-1/2 * log2(e)  (scores land in log2 domain)
__global__ __launch_bounds__(256) void rope_kernel(u16* q, u16* k,
    const float* __restrict__ cosT, const float* __restrict__ sinT) {
  int tid = blockIdx.x * 256 + threadIdx.x;   // 524288 = BH*N*8
  int row = tid >> 3, sub = tid & 7;
  int n = row & 2047;
  u32* qp = (u32*)(q + (size_t)row * 64 + sub * 8);
  u32* kp = (u32*)(k + (size_t)row * 64 + sub * 8);
  uint4 uq = *(uint4*)qp;
  uint4 uk = *(uint4*)kp;
  float4 c4 = *(const float4*)(cosT + n*32 + sub*4);
  float4 s4 = *(const float4*)(sinT + n*32 + sub*4);
  const float qs = 0.125f * 1.4426950408889634f;
#define ROPE_Q(u, c, s) { \
    float e = b2f((u16)(u)), o = b2f((u16)((u) >> 16)); \
    (u) = pkb((e*(c) - o*(s))*qs, (o*(c) + e*(s))*qs); }
#define ROPE_K(u, c, s) { \
    float e = b2f((u16)(u)), o = b2f((u16)((u) >> 16)); \
    (u) = pkb(e*(c) - o*(s), o*(c) + e*(s)); }
  ROPE_Q(uq.x, c4.x, s4.x) ROPE_Q(uq.y, c4.y, s4.y)
  ROPE_Q(uq.z, c4.z, s4.z) ROPE_Q(uq.w, c4.w, s4.w)
  ROPE_K(uk.x, c4.x, s4.x) ROPE_K(uk.y, c4.y, s4.y)
  ROPE_K(uk.z, c4.z, s4.z) ROPE_K(uk.w, c4.w, s4.w)
#undef ROPE_Q
#undef ROPE_K
  *(uint4*)qp = uq;
  *(uint4*)kp = uk;
}

// ---------------- Flash attention ----------------
// grid (N/128, BH), 8 waves x 16 q-rows (QBLK=128). KBLK=64. log2-domain.
// K,V staged in LDS: 3 buffers, 2-deep prefetch, counted vmcnt + raw barrier
// (T3/T4). Source-pre-swizzled staging; swapped QK^T; PV on V^T; O^T->O via LDS.
__global__ __launch_bounds__(512) void flash_attn(
    const u16* __restrict__ qbf, const u16* __restrict__ kbf,
    const u16* __restrict__ vt, u16* __restrict__ aout) {
  __shared__ __align__(16) char lK[3][8192];   // [key 64][128B], swizzled
  __shared__ __align__(16) char lV[3][8192];   // [d 64][128B], swizzled
  __shared__ __align__(16) char pl[8][2048];   // per-wave P / O-transpose buf
  int tid = threadIdx.x;
  int w = tid >> 6, lane = tid & 63;
  int l15 = lane & 15, g = lane >> 4;
  int qb = blockIdx.x, bh = blockIdx.y;
  const f32x4 z = {0.f, 0.f, 0.f, 0.f};
  const u16* qbase = qbf + ((size_t)bh*2048 + qb*128 + w*16) * 64;
  bf16x8 qa0 = *(const bf16x8*)(qbase + l15*64 + g*8);
  bf16x8 qa1 = *(const bf16x8*)(qbase + l15*64 + 32 + g*8);
  const char* kb = (const char*)(kbf + (size_t)bh * 2048 * 64);
  const char* vb = (const char*)(vt  + (size_t)bh * 64 * 2048);
  // staging: 512 threads x 16B = one 8KB tile each for K and V per iter
  int srow = tid >> 3;                 // 0..63 (K: key row; V: d row)
  int sb   = (tid & 7) * 16;
  int soff = sb ^ ((srow & 7) << 4);   // inverse-swizzled source
  char* pw = pl[w];
  const int swz = (l15 & 7) << 4;      // row-XOR swizzle (K/V/P)

  float m = -1e30f, ls = 0.f;
  f32x4 o[4];
  #pragma unroll
  for (int i = 0; i < 4; i++) o[i] = z;

#define STAGE(t, buf) { \
    gload16(kb + (size_t)((t)*64 + srow) * 128 + soff, &lK[buf][(size_t)tid*16]); \
    gload16(vb + (size_t)srow * 4096 + (t)*128 + soff, &lV[buf][(size_t)tid*16]); }

  // prologue: fill buffers 0 and 1
  STAGE(0, 0)
  STAGE(1, 1)
  asm volatile("s_waitcnt vmcnt(2)" ::: "memory");
  __builtin_amdgcn_s_barrier();

  int cur = 0, pfb = 2;
  #pragma unroll 1
  for (int t = 0; t < 32; ++t) {
    if (t < 30) STAGE(t + 2, pfb)
    const char* Kc = lK[cur];
    const char* Vc = lV[cur];
    // QK^T (swapped): st[kt] holds S^T[key = kt*16+g*4+r][q = l15]
    f32x4 st[4];
    __builtin_amdgcn_s_setprio(1);
    #pragma unroll
    for (int kt = 0; kt < 4; kt++) {
      const char* krow = Kc + (kt*16 + l15) * 128;
      bf16x8 k0 = *(const bf16x8*)(krow + ((g*16) ^ swz));
      bf16x8 k1 = *(const bf16x8*)(krow + ((64 + g*16) ^ swz));
      f32x4 a = mfma16(k0, qa0, z);
      st[kt] = mfma16(k1, qa1, a);
    }
    __builtin_amdgcn_s_setprio(0);
    // online softmax (log2 domain): lane owns 16 keys of q-col l15
    float mt = fmaxf(fmaxf(st[0][0], st[0][1]), fmaxf(st[0][2], st[0][3]));
    #pragma unroll
    for (int kt = 1; kt < 4; kt++)
      mt = fmaxf(mt, fmaxf(fmaxf(st[kt][0], st[kt][1]),
                           fmaxf(st[kt][2], st[kt][3])));
    mt = fmaxf(mt, __shfl_xor(mt, 16));
    mt = fmaxf(mt, __shfl_xor(mt, 32));
    // defer-max: only rescale when tile max grew past threshold
    if (__any(mt > m + 8.0f)) {
      float mn = fmaxf(m, mt);
      float al = __builtin_amdgcn_exp2f(m - mn);
      m = mn;
      ls *= al;
      #pragma unroll
      for (int dt = 0; dt < 4; dt++)
        #pragma unroll
        for (int r = 0; r < 4; r++)
          o[dt][r] *= al;
    }
    float rs = 0.f;
    #pragma unroll
    for (int kt = 0; kt < 4; kt++)
      #pragma unroll
      for (int r = 0; r < 4; r++) {
        float p = __builtin_amdgcn_exp2f(st[kt][r] - m);
        st[kt][r] = p;
        rs += p;
      }
    rs += __shfl_xor(rs, 16);
    rs += __shfl_xor(rs, 32);
    ls += rs;
    // pack P -> wave-private LDS row q=l15, bytes = key*2 (swizzled)
    #pragma unroll
    for (int kt = 0; kt < 4; kt++) {
      u32 lo = pkb(st[kt][0], st[kt][1]);
      u32 hi = pkb(st[kt][2], st[kt][3]);
      *(uint2*)(pw + l15*128 + ((kt*32 + g*8) ^ swz)) = make_uint2(lo, hi);
    }
    // P^T B-frags: lane = (q=l15, keys g*8..+7) per 32-key chunk
    bf16x8 pb0 = *(const bf16x8*)(pw + l15*128 + ((g*16) ^ swz));
    bf16x8 pb1 = *(const bf16x8*)(pw + l15*128 + ((64 + g*16) ^ swz));
    // PV: O^T[d = dt*16+g*4+r][q = l15]
    __builtin_amdgcn_s_setprio(1);
    #pragma unroll
    for (int dt = 0; dt < 4; dt++) {
      const char* vrow = Vc + (dt*16 + l15) * 128;
      bf16x8 v0 = *(const bf16x8*)(vrow + ((g*16) ^ swz));
      bf16x8 v1 = *(const bf16x8*)(vrow + ((64 + g*16) ^ swz));
      o[dt] = mfma16(v0, pb0, o[dt]);
      o[dt] = mfma16(v1, pb1, o[dt]);
    }
    __builtin_amdgcn_s_setprio(0);
    if (t < 31) {
      if (t < 30) { asm volatile("s_waitcnt vmcnt(2)" ::: "memory"); }
      else        { asm volatile("s_waitcnt vmcnt(0)" ::: "memory"); }
      __builtin_amdgcn_s_barrier();
    }
    cur = (cur + 1 == 3) ? 0 : cur + 1;
    pfb = (pfb + 1 == 3) ? 0 : pfb + 1;
  }
#undef STAGE

  // epilogue: O^T -> O via wave-private LDS, coalesced 16B stores
  float rls = 1.0f / ls;
  #pragma unroll
  for (int dt = 0; dt < 4; dt++)
    #pragma unroll
    for (int r = 0; r < 4; r++) {
      int d = dt*16 + g*4 + r;
      *(u16*)(pw + l15*128 + ((d*2) ^ swz)) = f2b(o[dt][r] * rls);
    }
  int b = bh >> 4, h = bh & 15;
  int rl = lane >> 3;
  #pragma unroll
  for (int i = 0; i < 2; i++) {
    int row = i*8 + rl;          // local q row within the wave's 16
    uint4 ov = *(const uint4*)(pw + row*128 + (((lane & 7)*16) ^ (rl << 4)));
    int n = qb*128 + w*16 + row;
    *(uint4*)(aout + ((size_t)(b*2048 + n))*1024 + h*64 + (lane & 7)*8) = ov;
  }
}

extern "C" void kernel_launch(void* const* d_in, const int* in_sizes, int n_in,
                              void* d_out, int out_size, void* d_ws, size_t ws_size,
                              hipStream_t stream) {
  const float* x    = (const float*)d_in[0];
  const float* lw   = (const float*)d_in[1];
  const float* lb   = (const float*)d_in[2];
  const float* wqkv = (const float*)d_in[3];
  const float* wout = (const float*)d_in[4];
  const float* bout = (const float*)d_in[5];
  float* out = (float*)d_out;

  char* ws = (char*)d_ws;
  size_t off = 0;
  auto alloc = [&](size_t bytes) {
    char* p = ws + off;
    off += (bytes + 255) & ~(size_t)255;
    return p;
  };
  u16* xn   = (u16*)alloc((size_t)ROWS_*DIM_*2);
  u16* wqt  = (u16*)alloc((size_t)3072*1024*2);
  u16* wot  = (u16*)alloc((size_t)1024*1024*2);
  u16* qb   = (u16*)alloc((size_t)BH_*2048*64*2);
  u16* kb   = (u16*)alloc((size_t)BH_*2048*64*2);
  u16* vtb  = (u16*)alloc((size_t)BH_*2048*64*2);
  u16* aout = (u16*)alloc((size_t)ROWS_*1024*2);
  float* cosT = (float*)alloc((size_t)2048*32*4);
  float* sinT = (float*)alloc((size_t)2048*32*4);

  rope_tables<<<256, 256, 0, stream>>>(cosT, sinT);
  ln_kernel<<<ROWS_, 256, 0, stream>>>(x, lw, lb, xn);
  transpose_f32_bf16<<<dim3(96, 32), 256, 0, stream>>>(wqkv, wqt, 1024, 3072);
  transpose_f32_bf16<<<dim3(32, 32), 256, 0, stream>>>(wout, wot, 1024, 1024);
  gemm_bt<0><<<dim3(32, 24), 256, 0, stream>>>(xn, wqt, 3072, 1024,
                                               qb, kb, vtb, nullptr, nullptr);
  rope_kernel<<<2048, 256, 0, stream>>>(qb, kb, cosT, sinT);
  flash_attn<<<dim3(16, 32), 512, 0, stream>>>(qb, kb, vtb, aout);
  gemm_bt<1><<<dim3(32, 8), 256, 0, stream>>>(aout, wot, 1024, 1024,
                                              nullptr, nullptr, nullptr, bout, out);
}